// Round 1
// baseline (621.964 us; speedup 1.0000x reference)
//
#include <hip/hip_runtime.h>
#include <hip/hip_bf16.h>
#include <math.h>

// Problem sizes (fixed by the reference)
constexpr int Bn  = 32;
constexpr int LK  = 2048;
constexpr int Dn  = 32;
constexpr int LQ  = 128;
constexpr int ET  = 128;
constexpr int Hn  = 8;
constexpr int ETK = 16;
constexpr int NH  = 128;
constexpr int SPLITS = 4;   // key-dim splits in attention

__device__ __forceinline__ float hsum4(float4 v){ return (v.x+v.y)+(v.z+v.w); }
__device__ __forceinline__ void fma4(float4& s, const float4 a, const float4 b){
  s.x = fmaf(a.x,b.x,s.x); s.y = fmaf(a.y,b.y,s.y);
  s.z = fmaf(a.z,b.z,s.z); s.w = fmaf(a.w,b.w,s.w);
}

// ---------------------------------------------------------------------------
// Kernel 1: time embedding + Q/K projection.
// grid = 1024 key-WGs (64 rows each) + 2 query-WGs; block = 128.
// Thread pair (2o,2o+1) holds half-rows of W in VGPRs; emb staged in LDS;
// halves merged with shfl_xor(1). 8 FMAs per LDS b128 broadcast read.
// ---------------------------------------------------------------------------
__global__ __launch_bounds__(128) void proj_kernel(
    const float* __restrict__ ts, const float* __restrict__ qt,
    const float* __restrict__ Wlin, const float* __restrict__ blin,
    const float* __restrict__ Wper, const float* __restrict__ bper,
    const float* __restrict__ Wq, const float* __restrict__ bq,
    const float* __restrict__ Wk, const float* __restrict__ bk,
    float* __restrict__ Kbuf, float* __restrict__ Qbuf)
{
  __shared__ __align__(16) float emb[64*ET];
  const int wg  = blockIdx.x;
  const int tid = threadIdx.x;
  const bool isq = (wg >= 1024);
  const int row0 = isq ? (wg - 1024)*64 : wg*64;
  const float* W    = isq ? Wq : Wk;
  const float* bias = isq ? bq : bk;
  const int op = tid >> 1, half = tid & 1;

  // two half-rows of the projection matrix in registers (128 VGPRs)
  float4 w0[16], w1[16];
  {
    const float4* r0 = (const float4*)(W + (2*op  )*ET + half*64);
    const float4* r1 = (const float4*)(W + (2*op+1)*ET + half*64);
    #pragma unroll
    for (int i=0;i<16;i++){ w0[i]=r0[i]; w1[i]=r1[i]; }
  }
  const float bo = bias[tid];

  // embedding column tid for 64 rows: col 0 linear, cols 1..127 sin
  const float wl = Wlin[0], bl = blin[0];
  float wp = 0.f, bp = 0.f;
  if (tid > 0){ wp = Wper[tid-1]; bp = bper[tid-1]; }
  for (int r=0;r<64;r++){
    const float t = isq ? qt[row0+r] : ts[row0+r];
    emb[r*ET + tid] = (tid==0) ? fmaf(t, wl, bl) : sinf(fmaf(t, wp, bp));
  }
  __syncthreads();

  for (int r=0;r<64;r++){
    const float4* e4 = (const float4*)(emb + r*ET + half*64);
    float4 a0 = {0,0,0,0}, a1 = {0,0,0,0};
    #pragma unroll
    for (int i=0;i<16;i++){ const float4 e = e4[i]; fma4(a0, w0[i], e); fma4(a1, w1[i], e); }
    float s0 = hsum4(a0), s1 = hsum4(a1);
    s0 += __shfl_xor(s0, 1);          // merge halves for output 2op
    s1 += __shfl_xor(s1, 1);          // merge halves for output 2op+1
    const float s = (half==0 ? s0 : s1) + bo;   // lane tid owns output o==tid
    const int o = tid;
    const int row = row0 + r;
    if (isq){
      // Q layout: (H, LQ, ETK)
      Qbuf[((o>>4)*LQ + row)*ETK + (o&15)] = s;
    } else {
      // K layout: (B, H, LK, ETK)
      const int b = row >> 11, lkey = row & (LK-1);
      Kbuf[(((b<<3) + (o>>4))*LK + lkey)*ETK + (o&15)] = s;
    }
  }
}

// ---------------------------------------------------------------------------
// Kernel 2: flash-style attention partials. grid = B*H*SPLITS = 1024, blk 128.
// Thread = one q row; online softmax over 512 keys (4 tiles of 128).
// ---------------------------------------------------------------------------
__global__ __launch_bounds__(128) void attn_kernel(
    const float* __restrict__ Kbuf, const float* __restrict__ Qbuf,
    const float* __restrict__ x,
    float* __restrict__ Pml, float* __restrict__ Pacc)
{
  __shared__ __align__(16) float kt[128*ETK];   // 8 KB
  __shared__ __align__(16) float xt[128*Dn];    // 16 KB
  const int wg = blockIdx.x;
  const int sp = wg & 3, h = (wg>>2)&7, b = wg>>5;
  const int q  = threadIdx.x;

  float4 qv[4];
  {
    const float4* Qr = (const float4*)(Qbuf + (h*LQ + q)*ETK);
    #pragma unroll
    for (int i=0;i<4;i++){
      qv[i]=Qr[i];
      qv[i].x*=0.25f; qv[i].y*=0.25f; qv[i].z*=0.25f; qv[i].w*=0.25f; // 1/sqrt(16)
    }
  }
  float m = -INFINITY, l = 0.f;
  float4 acc[8];
  #pragma unroll
  for (int d=0; d<8; d++) acc[d] = make_float4(0.f,0.f,0.f,0.f);

  for (int tt=0; tt<4; tt++){
    const int k0 = (sp*4 + tt)*128;
    {
      const float4* Ks = (const float4*)(Kbuf + ((size_t)(b*Hn+h)*LK + k0)*ETK);
      float4* kt4 = (float4*)kt;
      #pragma unroll
      for (int i=0;i<4;i++) kt4[q + i*128] = Ks[q + i*128];     // coalesced copy
      const float4* Xs = (const float4*)(x + (size_t)(b*LK + k0)*Dn);
      float4* xt4 = (float4*)xt;
      #pragma unroll
      for (int i=0;i<8;i++) xt4[q + i*128] = Xs[q + i*128];
    }
    __syncthreads();

    for (int c=0;c<8;c++){                 // 16-key chunks
      float sc[16];
      #pragma unroll
      for (int j=0;j<16;j++){
        const float4* kr = (const float4*)(kt + (c*16+j)*ETK); // broadcast read
        float4 a = {0,0,0,0};
        #pragma unroll
        for (int i=0;i<4;i++) fma4(a, qv[i], kr[i]);
        sc[j] = hsum4(a);
      }
      float cmax = sc[0];
      #pragma unroll
      for (int j=1;j<16;j++) cmax = fmaxf(cmax, sc[j]);
      const float mn = fmaxf(m, cmax);
      const float alpha = __expf(m - mn);  // first chunk: exp(-inf)=0, safe
      l *= alpha;
      #pragma unroll
      for (int d=0;d<8;d++){ acc[d].x*=alpha; acc[d].y*=alpha; acc[d].z*=alpha; acc[d].w*=alpha; }
      #pragma unroll
      for (int j=0;j<16;j++){
        const float p = __expf(sc[j] - mn);
        l += p;
        const float4* xr = (const float4*)(xt + (c*16+j)*Dn);  // broadcast read
        #pragma unroll
        for (int d=0;d<8;d++){
          acc[d].x = fmaf(p, xr[d].x, acc[d].x);
          acc[d].y = fmaf(p, xr[d].y, acc[d].y);
          acc[d].z = fmaf(p, xr[d].z, acc[d].z);
          acc[d].w = fmaf(p, xr[d].w, acc[d].w);
        }
      }
      m = mn;
    }
    __syncthreads();
  }
  const int pidx = ((b*Hn + h)*SPLITS + sp)*LQ + q;
  Pml[pidx*2]   = m;
  Pml[pidx*2+1] = l;
  float4* Pa = (float4*)(Pacc + (size_t)pidx*32);
  #pragma unroll
  for (int d=0;d<8;d++) Pa[d] = acc[d];
}

// ---------------------------------------------------------------------------
// Kernel 3: merge the SPLITS partials -> att rows (B, LQ, H*D) h-major.
// ---------------------------------------------------------------------------
__global__ __launch_bounds__(256) void combine_kernel(
    const float* __restrict__ Pml, const float* __restrict__ Pacc,
    float* __restrict__ att)
{
  const int T = blockIdx.x*256 + threadIdx.x;   // 32768 = B*H*LQ
  const int q = T & (LQ-1), h = (T>>7) & (Hn-1), b = T>>10;
  const int base = (b*Hn + h)*SPLITS*LQ + q;
  float ms[SPLITS], ls[SPLITS];
  float mstar = -INFINITY;
  #pragma unroll
  for (int s=0;s<SPLITS;s++){
    ms[s] = Pml[(base + s*LQ)*2];
    ls[s] = Pml[(base + s*LQ)*2 + 1];
    mstar = fmaxf(mstar, ms[s]);
  }
  float den = 0.f, w[SPLITS];
  #pragma unroll
  for (int s=0;s<SPLITS;s++){ w[s] = __expf(ms[s]-mstar); den = fmaf(ls[s], w[s], den); }
  const float inv = 1.f/den;
  float4 o[8];
  #pragma unroll
  for (int d=0;d<8;d++) o[d] = make_float4(0.f,0.f,0.f,0.f);
  #pragma unroll
  for (int s=0;s<SPLITS;s++){
    const float ws = w[s]*inv;
    const float4* Pa = (const float4*)(Pacc + (size_t)(base + s*LQ)*32);
    #pragma unroll
    for (int d=0;d<8;d++){
      o[d].x = fmaf(ws, Pa[d].x, o[d].x);
      o[d].y = fmaf(ws, Pa[d].y, o[d].y);
      o[d].z = fmaf(ws, Pa[d].z, o[d].z);
      o[d].w = fmaf(ws, Pa[d].w, o[d].w);
    }
  }
  float4* dst = (float4*)(att + (size_t)(b*LQ + q)*(Hn*Dn) + h*Dn);
  #pragma unroll
  for (int d=0;d<8;d++) dst[d] = o[d];
}

// ---------------------------------------------------------------------------
// Kernel 4: out = att @ Wo^T + bo. 16 rows/WG, weight half-rows in VGPRs.
// ---------------------------------------------------------------------------
__global__ __launch_bounds__(256) void outproj_kernel(
    const float* __restrict__ att, const float* __restrict__ Wo, const float* __restrict__ bo,
    float* __restrict__ outb)
{
  __shared__ __align__(16) float a[16*256];   // 16 KB
  const int tid = threadIdx.x;
  const int o = tid>>1, half = tid&1;
  float4 w[32];
  {
    const float4* Wr = (const float4*)(Wo + o*256 + half*128);
    #pragma unroll
    for (int i=0;i<32;i++) w[i]=Wr[i];
  }
  const int row0 = blockIdx.x*16;
  {
    const float4* src = (const float4*)(att + (size_t)row0*256);
    float4* a4 = (float4*)a;
    #pragma unroll
    for (int i=0;i<4;i++) a4[tid + i*256] = src[tid + i*256];
  }
  __syncthreads();
  for (int r=0;r<16;r++){
    const float4* ar = (const float4*)(a + r*256 + half*128);
    float4 s4 = {0,0,0,0};
    #pragma unroll
    for (int i=0;i<32;i++) fma4(s4, w[i], ar[i]);
    float s = hsum4(s4);
    s += __shfl_xor(s, 1);
    if (half==0) outb[(size_t)(row0+r)*NH + o] = s + bo[o];
  }
}

// ---------------------------------------------------------------------------
// Kernel 5: x_gates = out @ W_ih^T + b_ih. 384 threads, full rows in VGPRs.
// ---------------------------------------------------------------------------
__global__ __launch_bounds__(384) void gates_kernel(
    const float* __restrict__ outb, const float* __restrict__ W_ih, const float* __restrict__ b_ih,
    float* __restrict__ gates)
{
  __shared__ __align__(16) float a[16*128];   // 8 KB
  const int tid = threadIdx.x;
  float4 w[32];
  {
    const float4* Wr = (const float4*)(W_ih + (size_t)tid*NH);
    #pragma unroll
    for (int i=0;i<32;i++) w[i]=Wr[i];
  }
  const float bi = b_ih[tid];
  const int row0 = blockIdx.x*16;
  {
    const float4* src = (const float4*)(outb + (size_t)row0*NH);
    float4* a4 = (float4*)a;
    for (int i=tid; i<512; i+=384) a4[i] = src[i];
  }
  __syncthreads();
  for (int r=0;r<16;r++){
    const float4* ar = (const float4*)(a + r*NH);
    float4 s0={0,0,0,0}, s1={0,0,0,0};
    #pragma unroll
    for (int i=0;i<16;i++){ fma4(s0, w[2*i], ar[2*i]); fma4(s1, w[2*i+1], ar[2*i+1]); }
    gates[(size_t)(row0+r)*384 + tid] = hsum4(s0) + hsum4(s1) + bi;
  }
}

// ---------------------------------------------------------------------------
// Kernel 6: GRU scan (128 steps) + classifier MLP, one WG per batch element.
// W_hh row pinned in VGPRs; h ping-pongs through LDS; 2 barriers/step.
// ---------------------------------------------------------------------------
__global__ __launch_bounds__(384) void gru_cls_kernel(
    const float* __restrict__ gates, const float* __restrict__ W_hh, const float* __restrict__ b_hh,
    const float* __restrict__ W1, const float* __restrict__ b1,
    const float* __restrict__ W2, const float* __restrict__ b2,
    const float* __restrict__ W3, const float* __restrict__ b3,
    float* __restrict__ out)
{
  __shared__ __align__(16) float h[128];
  __shared__ __align__(16) float hg[384];
  __shared__ __align__(16) float c1[300];
  __shared__ __align__(16) float c2[300];
  const int b = blockIdx.x, j = threadIdx.x;
  float4 w[32];
  {
    const float4* Wr = (const float4*)(W_hh + (size_t)j*NH);
    #pragma unroll
    for (int i=0;i<32;i++) w[i]=Wr[i];
  }
  const float bh = b_hh[j];
  if (j < 128) h[j] = 0.f;
  __syncthreads();

  for (int t=0;t<LQ;t++){
    const float4* h4 = (const float4*)h;
    float4 s0={0,0,0,0}, s1={0,0,0,0};
    #pragma unroll
    for (int i=0;i<16;i++){ fma4(s0, w[2*i], h4[2*i]); fma4(s1, w[2*i+1], h4[2*i+1]); }
    hg[j] = hsum4(s0) + hsum4(s1) + bh;
    __syncthreads();                       // hg visible; all h reads done
    if (j < 128){
      const size_t base = (size_t)(b*LQ + t)*384 + j;
      const float xr = gates[base], xz = gates[base+128], xn = gates[base+256];
      const float r = 1.f/(1.f + expf(-(xr + hg[j])));
      const float z = 1.f/(1.f + expf(-(xz + hg[j+128])));
      const float n = tanhf(fmaf(r, hg[j+256], xn));
      h[j] = (1.f - z)*n + z*h[j];
    }
    __syncthreads();                       // h updated before next dot
  }

  // classifier head on h_last
  if (j < 300){
    const float4* Wr1 = (const float4*)(W1 + (size_t)j*128);
    const float4* h4 = (const float4*)h;
    float4 s={0,0,0,0};
    #pragma unroll
    for (int i=0;i<32;i++) fma4(s, Wr1[i], h4[i]);
    c1[j] = fmaxf(hsum4(s) + b1[j], 0.f);
  }
  __syncthreads();
  if (j < 300){
    const float4* Wr2 = (const float4*)(W2 + (size_t)j*300);  // 300 floats = 75 float4, 16B-aligned rows
    const float4* c14 = (const float4*)c1;
    float4 s={0,0,0,0};
    #pragma unroll
    for (int i=0;i<75;i++) fma4(s, Wr2[i], c14[i]);
    c2[j] = fmaxf(hsum4(s) + b2[j], 0.f);
  }
  __syncthreads();
  if (j < 2){
    const float4* Wr3 = (const float4*)(W3 + (size_t)j*300);
    const float4* c24 = (const float4*)c2;
    float4 s={0,0,0,0};
    #pragma unroll
    for (int i=0;i<75;i++) fma4(s, Wr3[i], c24[i]);
    out[b*2 + j] = hsum4(s) + b3[j];
  }
}

// ---------------------------------------------------------------------------
extern "C" void kernel_launch(void* const* d_in, const int* in_sizes, int n_in,
                              void* d_out, int out_size, void* d_ws, size_t ws_size,
                              hipStream_t stream)
{
  const float* x    = (const float*)d_in[0];
  const float* ts   = (const float*)d_in[1];
  const float* qt   = (const float*)d_in[2];
  const float* Wlin = (const float*)d_in[3];
  const float* blin = (const float*)d_in[4];
  const float* Wper = (const float*)d_in[5];
  const float* bper = (const float*)d_in[6];
  const float* Wq   = (const float*)d_in[7];
  const float* bq   = (const float*)d_in[8];
  const float* Wk   = (const float*)d_in[9];
  const float* bk   = (const float*)d_in[10];
  const float* Wo   = (const float*)d_in[11];
  const float* bo   = (const float*)d_in[12];
  const float* W_ih = (const float*)d_in[13];
  const float* b_ih = (const float*)d_in[14];
  const float* W_hh = (const float*)d_in[15];
  const float* b_hh = (const float*)d_in[16];
  const float* W1   = (const float*)d_in[17];
  const float* b1   = (const float*)d_in[18];
  const float* W2   = (const float*)d_in[19];
  const float* b2   = (const float*)d_in[20];
  const float* W3   = (const float*)d_in[21];
  const float* b3   = (const float*)d_in[22];
  float* out = (float*)d_out;
  float* ws  = (float*)d_ws;

  // workspace layout (floats), all 16B-aligned
  float* Kbuf = ws;                        // B*H*LK*ETK      = 8,388,608
  float* Qbuf = Kbuf + 8388608;            // H*LQ*ETK        = 16,384
  float* Pml  = Qbuf + 16384;              // B*H*S*LQ*2      = 262,144
  float* Pacc = Pml  + 262144;             // B*H*S*LQ*32     = 4,194,304
  float* attb = Pacc + 4194304;            // B*LQ*256        = 1,048,576
  float* outb = attb + 1048576;            // B*LQ*128        = 524,288
  float* gts  = outb + 524288;             // B*LQ*384        = 1,572,864
  (void)ws_size; (void)in_sizes; (void)n_in; (void)out_size;

  proj_kernel   <<<dim3(1026), dim3(128), 0, stream>>>(ts, qt, Wlin, blin, Wper, bper, Wq, bq, Wk, bk, Kbuf, Qbuf);
  attn_kernel   <<<dim3(1024), dim3(128), 0, stream>>>(Kbuf, Qbuf, x, Pml, Pacc);
  combine_kernel<<<dim3(128),  dim3(256), 0, stream>>>(Pml, Pacc, attb);
  outproj_kernel<<<dim3(256),  dim3(256), 0, stream>>>(attb, Wo, bo, outb);
  gates_kernel  <<<dim3(256),  dim3(384), 0, stream>>>(outb, W_ih, b_ih, gts);
  gru_cls_kernel<<<dim3(32),   dim3(384), 0, stream>>>(gts, W_hh, b_hh, W1, b1, W2, b2, W3, b3, out);
}

// Round 3
// 543.458 us; speedup vs baseline: 1.1445x; 1.1445x over previous
//
#include <hip/hip_runtime.h>
#include <hip/hip_bf16.h>
#include <math.h>

// Problem sizes (fixed by the reference)
constexpr int Bn  = 32;
constexpr int LK  = 2048;
constexpr int Dn  = 32;
constexpr int LQ  = 128;
constexpr int ET  = 128;
constexpr int Hn  = 8;
constexpr int ETK = 16;
constexpr int NH  = 128;
constexpr int SPLITS = 4;   // key-dim splits in attention

__device__ __forceinline__ float hsum4(float4 v){ return (v.x+v.y)+(v.z+v.w); }
__device__ __forceinline__ void fma4(float4& s, const float4 a, const float4 b){
  s.x = fmaf(a.x,b.x,s.x); s.y = fmaf(a.y,b.y,s.y);
  s.z = fmaf(a.z,b.z,s.z); s.w = fmaf(a.w,b.w,s.w);
}

// ---------------------------------------------------------------------------
// Kernel 1: time embedding + Q/K projection.
// grid = 1024 key-WGs (64 rows each) + 2 query-WGs; block = 128.
// ---------------------------------------------------------------------------
__global__ __launch_bounds__(128) void proj_kernel(
    const float* __restrict__ ts, const float* __restrict__ qt,
    const float* __restrict__ Wlin, const float* __restrict__ blin,
    const float* __restrict__ Wper, const float* __restrict__ bper,
    const float* __restrict__ Wq, const float* __restrict__ bq,
    const float* __restrict__ Wk, const float* __restrict__ bk,
    float* __restrict__ Kbuf, float* __restrict__ Qbuf)
{
  __shared__ __align__(16) float emb[64*ET];
  const int wg  = blockIdx.x;
  const int tid = threadIdx.x;
  const bool isq = (wg >= 1024);
  const int row0 = isq ? (wg - 1024)*64 : wg*64;
  const float* W    = isq ? Wq : Wk;
  const float* bias = isq ? bq : bk;
  const int op = tid >> 1, half = tid & 1;

  // two half-rows of the projection matrix in registers
  float4 w0[16], w1[16];
  {
    const float4* r0 = (const float4*)(W + (2*op  )*ET + half*64);
    const float4* r1 = (const float4*)(W + (2*op+1)*ET + half*64);
    #pragma unroll
    for (int i=0;i<16;i++){ w0[i]=r0[i]; w1[i]=r1[i]; }
  }
  const float bo = bias[tid];

  const float wl = Wlin[0], bl = blin[0];
  float wp = 0.f, bp = 0.f;
  if (tid > 0){ wp = Wper[tid-1]; bp = bper[tid-1]; }
  for (int r=0;r<64;r++){
    const float t = isq ? qt[row0+r] : ts[row0+r];
    emb[r*ET + tid] = (tid==0) ? fmaf(t, wl, bl) : __sinf(fmaf(t, wp, bp));
  }
  __syncthreads();

  for (int r=0;r<64;r++){
    const float4* e4 = (const float4*)(emb + r*ET + half*64);
    float4 a0 = {0,0,0,0}, a1 = {0,0,0,0};
    #pragma unroll
    for (int i=0;i<16;i++){ const float4 e = e4[i]; fma4(a0, w0[i], e); fma4(a1, w1[i], e); }
    float s0 = hsum4(a0), s1 = hsum4(a1);
    s0 += __shfl_xor(s0, 1);
    s1 += __shfl_xor(s1, 1);
    const float s = (half==0 ? s0 : s1) + bo;   // lane tid owns output o==tid
    const int o = tid;
    const int row = row0 + r;
    if (isq){
      Qbuf[((o>>4)*LQ + row)*ETK + (o&15)] = s;            // (H, LQ, ETK)
    } else {
      const int b = row >> 11, lkey = row & (LK-1);
      Kbuf[(((b<<3) + (o>>4))*LK + lkey)*ETK + (o&15)] = s; // (B, H, LK, ETK)
    }
  }
}

// ---------------------------------------------------------------------------
// Kernel 2: flash-style attention partials.
// grid = B*(H/2)*SPLITS = 512, block 128 = 2 waves.
// wave w handles head hp*2+w; waves SHARE the x tile; each lane owns TWO
// q-rows (lane, lane+64) so every broadcast LDS read feeds 2x the FMAs.
// ---------------------------------------------------------------------------
__global__ __launch_bounds__(128) void attn_kernel(
    const float* __restrict__ Kbuf, const float* __restrict__ Qbuf,
    const float* __restrict__ x,
    float* __restrict__ Pml, float* __restrict__ Pacc)
{
  __shared__ __align__(16) float kt[2*128*ETK];   // 16 KB (one 128-key tile per head)
  __shared__ __align__(16) float xt[128*Dn];      // 16 KB
  const int wg = blockIdx.x;
  const int sp = wg & 3, hp = (wg>>2)&3, b = wg>>4;
  const int tid = threadIdx.x;
  const int w = tid >> 6, lane = tid & 63;
  const int h = hp*2 + w;

  float4 qv0[4], qv1[4];
  {
    const float4* Q0 = (const float4*)(Qbuf + (h*LQ + lane     )*ETK);
    const float4* Q1 = (const float4*)(Qbuf + (h*LQ + lane + 64)*ETK);
    #pragma unroll
    for (int i=0;i<4;i++){
      qv0[i]=Q0[i]; qv1[i]=Q1[i];
      qv0[i].x*=0.25f; qv0[i].y*=0.25f; qv0[i].z*=0.25f; qv0[i].w*=0.25f;
      qv1[i].x*=0.25f; qv1[i].y*=0.25f; qv1[i].z*=0.25f; qv1[i].w*=0.25f;
    }
  }
  float m0=-INFINITY, l0=0.f, m1=-INFINITY, l1=0.f;
  float4 acc0[8], acc1[8];
  #pragma unroll
  for (int d=0; d<8; d++){ acc0[d]=make_float4(0,0,0,0); acc1[d]=make_float4(0,0,0,0); }

  for (int tt=0; tt<4; tt++){
    const int k0 = sp*512 + tt*128;
    {
      const float4* Ks = (const float4*)(Kbuf + ((size_t)(b*Hn+h)*LK + k0)*ETK);
      float4* kd = ((float4*)kt) + w*512;
      #pragma unroll
      for (int i=0;i<8;i++) kd[lane + i*64] = Ks[lane + i*64];
      const float4* Xs = (const float4*)(x + (size_t)(b*LK + k0)*Dn);
      float4* xd = (float4*)xt;
      #pragma unroll
      for (int i=0;i<8;i++) xd[tid + i*128] = Xs[tid + i*128];
    }
    __syncthreads();

    for (int c=0;c<8;c++){                 // 16-key chunks
      float sc0[16], sc1[16];
      #pragma unroll
      for (int j=0;j<16;j++){
        const float4* kr = ((const float4*)kt) + w*512 + (c*16+j)*4; // broadcast
        float4 a0={0,0,0,0}, a1={0,0,0,0};
        #pragma unroll
        for (int i=0;i<4;i++){ const float4 k4=kr[i]; fma4(a0, qv0[i], k4); fma4(a1, qv1[i], k4); }
        sc0[j]=hsum4(a0); sc1[j]=hsum4(a1);
      }
      float c0 = sc0[0], c1 = sc1[0];
      #pragma unroll
      for (int j=1;j<16;j++){ c0=fmaxf(c0,sc0[j]); c1=fmaxf(c1,sc1[j]); }
      const float mn0 = fmaxf(m0,c0), mn1 = fmaxf(m1,c1);
      if (__any(mn0>m0 || mn1>m1)){
        const float a0 = __expf(m0-mn0), a1 = __expf(m1-mn1);
        l0*=a0; l1*=a1;
        #pragma unroll
        for (int d=0;d<8;d++){
          acc0[d].x*=a0; acc0[d].y*=a0; acc0[d].z*=a0; acc0[d].w*=a0;
          acc1[d].x*=a1; acc1[d].y*=a1; acc1[d].z*=a1; acc1[d].w*=a1;
        }
        m0=mn0; m1=mn1;
      }
      #pragma unroll
      for (int j=0;j<16;j++){
        const float p0 = __expf(sc0[j]-m0), p1 = __expf(sc1[j]-m1);
        l0+=p0; l1+=p1;
        const float4* xr = ((const float4*)xt) + (c*16+j)*8;   // broadcast
        #pragma unroll
        for (int d=0;d<8;d++){
          const float4 x4 = xr[d];
          acc0[d].x = fmaf(p0,x4.x,acc0[d].x); acc0[d].y = fmaf(p0,x4.y,acc0[d].y);
          acc0[d].z = fmaf(p0,x4.z,acc0[d].z); acc0[d].w = fmaf(p0,x4.w,acc0[d].w);
          acc1[d].x = fmaf(p1,x4.x,acc1[d].x); acc1[d].y = fmaf(p1,x4.y,acc1[d].y);
          acc1[d].z = fmaf(p1,x4.z,acc1[d].z); acc1[d].w = fmaf(p1,x4.w,acc1[d].w);
        }
      }
    }
    __syncthreads();
  }
  const int pidx0 = ((b*Hn + h)*SPLITS + sp)*LQ + lane;
  const int pidx1 = pidx0 + 64;
  Pml[pidx0*2] = m0;  Pml[pidx0*2+1] = l0;
  Pml[pidx1*2] = m1;  Pml[pidx1*2+1] = l1;
  float4* Pa0 = (float4*)(Pacc + (size_t)pidx0*32);
  float4* Pa1 = (float4*)(Pacc + (size_t)pidx1*32);
  #pragma unroll
  for (int d=0;d<8;d++){ Pa0[d]=acc0[d]; Pa1[d]=acc1[d]; }
}

// ---------------------------------------------------------------------------
// Kernel 3: merge the SPLITS partials -> att rows (B, LQ, H*D) h-major.
// ---------------------------------------------------------------------------
__global__ __launch_bounds__(256) void combine_kernel(
    const float* __restrict__ Pml, const float* __restrict__ Pacc,
    float* __restrict__ att)
{
  const int T = blockIdx.x*256 + threadIdx.x;   // 32768 = B*H*LQ
  const int q = T & (LQ-1), h = (T>>7) & (Hn-1), b = T>>10;
  const int base = (b*Hn + h)*SPLITS*LQ + q;
  float ms[SPLITS], ls[SPLITS];
  float mstar = -INFINITY;
  #pragma unroll
  for (int s=0;s<SPLITS;s++){
    ms[s] = Pml[(base + s*LQ)*2];
    ls[s] = Pml[(base + s*LQ)*2 + 1];
    mstar = fmaxf(mstar, ms[s]);
  }
  float den = 0.f, wsc[SPLITS];
  #pragma unroll
  for (int s=0;s<SPLITS;s++){ wsc[s] = __expf(ms[s]-mstar); den = fmaf(ls[s], wsc[s], den); }
  const float inv = 1.f/den;
  float4 o[8];
  #pragma unroll
  for (int d=0;d<8;d++) o[d] = make_float4(0.f,0.f,0.f,0.f);
  #pragma unroll
  for (int s=0;s<SPLITS;s++){
    const float ws = wsc[s]*inv;
    const float4* Pa = (const float4*)(Pacc + (size_t)(base + s*LQ)*32);
    #pragma unroll
    for (int d=0;d<8;d++){
      o[d].x = fmaf(ws, Pa[d].x, o[d].x);
      o[d].y = fmaf(ws, Pa[d].y, o[d].y);
      o[d].z = fmaf(ws, Pa[d].z, o[d].z);
      o[d].w = fmaf(ws, Pa[d].w, o[d].w);
    }
  }
  float4* dst = (float4*)(att + (size_t)(b*LQ + q)*(Hn*Dn) + h*Dn);
  #pragma unroll
  for (int d=0;d<8;d++) dst[d] = o[d];
}

// ---------------------------------------------------------------------------
// Kernel 4: out = att @ Wo^T + bo. 16 rows/WG, weight half-rows in VGPRs.
// ---------------------------------------------------------------------------
__global__ __launch_bounds__(256) void outproj_kernel(
    const float* __restrict__ att, const float* __restrict__ Wo, const float* __restrict__ bo,
    float* __restrict__ outb)
{
  __shared__ __align__(16) float a[16*256];   // 16 KB
  const int tid = threadIdx.x;
  const int o = tid>>1, half = tid&1;
  float4 w[32];
  {
    const float4* Wr = (const float4*)(Wo + o*256 + half*128);
    #pragma unroll
    for (int i=0;i<32;i++) w[i]=Wr[i];
  }
  const int row0 = blockIdx.x*16;
  {
    const float4* src = (const float4*)(att + (size_t)row0*256);
    float4* a4 = (float4*)a;
    #pragma unroll
    for (int i=0;i<4;i++) a4[tid + i*256] = src[tid + i*256];
  }
  __syncthreads();
  for (int r=0;r<16;r++){
    const float4* ar = (const float4*)(a + r*256 + half*128);
    float4 s4 = {0,0,0,0};
    #pragma unroll
    for (int i=0;i<32;i++) fma4(s4, w[i], ar[i]);
    float s = hsum4(s4);
    s += __shfl_xor(s, 1);
    if (half==0) outb[(size_t)(row0+r)*NH + o] = s + bo[o];
  }
}

// ---------------------------------------------------------------------------
// Kernel 5: x_gates = out @ W_ih^T + b_ih. 384 threads, full rows in VGPRs.
// ---------------------------------------------------------------------------
__global__ __launch_bounds__(384) void gates_kernel(
    const float* __restrict__ outb, const float* __restrict__ W_ih, const float* __restrict__ b_ih,
    float* __restrict__ gates)
{
  __shared__ __align__(16) float a[16*128];   // 8 KB
  const int tid = threadIdx.x;
  float4 w[32];
  {
    const float4* Wr = (const float4*)(W_ih + (size_t)tid*NH);
    #pragma unroll
    for (int i=0;i<32;i++) w[i]=Wr[i];
  }
  const float bi = b_ih[tid];
  const int row0 = blockIdx.x*16;
  {
    const float4* src = (const float4*)(outb + (size_t)row0*NH);
    float4* a4 = (float4*)a;
    for (int i=tid; i<512; i+=384) a4[i] = src[i];
  }
  __syncthreads();
  for (int r=0;r<16;r++){
    const float4* ar = (const float4*)(a + r*NH);
    float4 s0={0,0,0,0}, s1={0,0,0,0};
    #pragma unroll
    for (int i=0;i<16;i++){ fma4(s0, w[2*i], ar[2*i]); fma4(s1, w[2*i+1], ar[2*i+1]); }
    gates[(size_t)(row0+r)*384 + tid] = hsum4(s0) + hsum4(s1) + bi;
  }
}

// ---------------------------------------------------------------------------
// Kernel 6: GRU scan (128 steps) + classifier MLP, one WG per batch element.
// 768 threads: thread pair (2o,2o+1) holds HALF-rows of W_hh (16 float4 =
// 64 VGPR -> stays register-resident), merged via shfl_xor(1). Next-step
// gates prefetched at loop top to hide the only global load.
// ---------------------------------------------------------------------------
__global__ __launch_bounds__(768) void gru_cls_kernel(
    const float* __restrict__ gates, const float* __restrict__ W_hh, const float* __restrict__ b_hh,
    const float* __restrict__ W1, const float* __restrict__ b1,
    const float* __restrict__ W2, const float* __restrict__ b2,
    const float* __restrict__ W3, const float* __restrict__ b3,
    float* __restrict__ out)
{
  __shared__ __align__(16) float h[128];
  __shared__ __align__(16) float hg[384];
  __shared__ __align__(16) float c1[304];
  __shared__ __align__(16) float c2[304];
  const int b = blockIdx.x, t = threadIdx.x;
  const int op = t >> 1, half = t & 1;

  float4 w[16];
  {
    const float4* Wr = (const float4*)(W_hh + (size_t)op*NH + half*64);
    #pragma unroll
    for (int i=0;i<16;i++) w[i]=Wr[i];
  }
  const float bh = b_hh[op];

  float gxr=0.f, gxz=0.f, gxn=0.f;
  if (t < 128){
    const size_t gb = (size_t)b*LQ*384 + t;
    gxr = gates[gb]; gxz = gates[gb+128]; gxn = gates[gb+256];
    h[t] = 0.f;
  }
  __syncthreads();

  for (int tt=0; tt<LQ; tt++){
    // prefetch next step's gates early (latency hidden by matvec+barriers)
    float nxr=0.f, nxz=0.f, nxn=0.f;
    if (t < 128 && tt+1 < LQ){
      const size_t nb = ((size_t)b*LQ + tt + 1)*384 + t;
      nxr = gates[nb]; nxz = gates[nb+128]; nxn = gates[nb+256];
    }
    const float4* h4 = ((const float4*)h) + half*16;
    float4 s0={0,0,0,0}, s1={0,0,0,0}, s2={0,0,0,0}, s3={0,0,0,0};
    #pragma unroll
    for (int i=0;i<4;i++){
      fma4(s0, w[4*i  ], h4[4*i  ]);
      fma4(s1, w[4*i+1], h4[4*i+1]);
      fma4(s2, w[4*i+2], h4[4*i+2]);
      fma4(s3, w[4*i+3], h4[4*i+3]);
    }
    s0.x+=s1.x; s0.y+=s1.y; s0.z+=s1.z; s0.w+=s1.w;
    s2.x+=s3.x; s2.y+=s3.y; s2.z+=s3.z; s2.w+=s3.w;
    s0.x+=s2.x; s0.y+=s2.y; s0.z+=s2.z; s0.w+=s2.w;
    float s = hsum4(s0);
    s += __shfl_xor(s, 1);
    if (half==0) hg[op] = s + bh;
    __syncthreads();
    if (t < 128){
      const float r = 1.f/(1.f + __expf(-(gxr + hg[t])));
      const float z = 1.f/(1.f + __expf(-(gxz + hg[t+128])));
      const float n = 1.f - 2.f/(1.f + __expf(2.f*fmaf(r, hg[t+256], gxn)));
      h[t] = (1.f - z)*n + z*h[t];
      gxr = nxr; gxz = nxz; gxn = nxn;
    }
    __syncthreads();
  }

  // classifier head on h_last
  if (t < 300){
    const float4* Wr1 = (const float4*)(W1 + (size_t)t*128);
    const float4* h4 = (const float4*)h;
    float4 s={0,0,0,0};
    #pragma unroll
    for (int i=0;i<32;i++) fma4(s, Wr1[i], h4[i]);
    c1[t] = fmaxf(hsum4(s) + b1[t], 0.f);
  }
  __syncthreads();
  if (t < 300){
    const float4* Wr2 = (const float4*)(W2 + (size_t)t*300);
    const float4* c14 = (const float4*)c1;
    float4 s={0,0,0,0};
    #pragma unroll
    for (int i=0;i<75;i++) fma4(s, Wr2[i], c14[i]);
    c2[t] = fmaxf(hsum4(s) + b2[t], 0.f);
  }
  __syncthreads();
  if (t < 2){
    const float4* Wr3 = (const float4*)(W3 + (size_t)t*300);
    const float4* c24 = (const float4*)c2;
    float4 s={0,0,0,0};
    #pragma unroll
    for (int i=0;i<75;i++) fma4(s, Wr3[i], c24[i]);
    out[b*2 + t] = hsum4(s) + b3[t];
  }
}

// ---------------------------------------------------------------------------
extern "C" void kernel_launch(void* const* d_in, const int* in_sizes, int n_in,
                              void* d_out, int out_size, void* d_ws, size_t ws_size,
                              hipStream_t stream)
{
  const float* x    = (const float*)d_in[0];
  const float* ts   = (const float*)d_in[1];
  const float* qt   = (const float*)d_in[2];
  const float* Wlin = (const float*)d_in[3];
  const float* blin = (const float*)d_in[4];
  const float* Wper = (const float*)d_in[5];
  const float* bper = (const float*)d_in[6];
  const float* Wq   = (const float*)d_in[7];
  const float* bq   = (const float*)d_in[8];
  const float* Wk   = (const float*)d_in[9];
  const float* bk   = (const float*)d_in[10];
  const float* Wo   = (const float*)d_in[11];
  const float* bo   = (const float*)d_in[12];
  const float* W_ih = (const float*)d_in[13];
  const float* b_ih = (const float*)d_in[14];
  const float* W_hh = (const float*)d_in[15];
  const float* b_hh = (const float*)d_in[16];
  const float* W1   = (const float*)d_in[17];
  const float* b1   = (const float*)d_in[18];
  const float* W2   = (const float*)d_in[19];
  const float* b2   = (const float*)d_in[20];
  const float* W3   = (const float*)d_in[21];
  const float* b3   = (const float*)d_in[22];
  float* out = (float*)d_out;
  float* ws  = (float*)d_ws;

  // workspace layout (floats), all 16B-aligned
  float* Kbuf = ws;                        // B*H*LK*ETK      = 8,388,608
  float* Qbuf = Kbuf + 8388608;            // H*LQ*ETK        = 16,384
  float* Pml  = Qbuf + 16384;              // B*H*S*LQ*2      = 262,144
  float* Pacc = Pml  + 262144;             // B*H*S*LQ*32     = 4,194,304
  float* attb = Pacc + 4194304;            // B*LQ*256        = 1,048,576
  float* outb = attb + 1048576;            // B*LQ*128        = 524,288
  float* gts  = outb + 524288;             // B*LQ*384        = 1,572,864
  (void)ws_size; (void)in_sizes; (void)n_in; (void)out_size;

  proj_kernel   <<<dim3(1026), dim3(128), 0, stream>>>(ts, qt, Wlin, blin, Wper, bper, Wq, bq, Wk, bk, Kbuf, Qbuf);
  attn_kernel   <<<dim3(512),  dim3(128), 0, stream>>>(Kbuf, Qbuf, x, Pml, Pacc);
  combine_kernel<<<dim3(128),  dim3(256), 0, stream>>>(Pml, Pacc, attb);
  outproj_kernel<<<dim3(256),  dim3(256), 0, stream>>>(attb, Wo, bo, outb);
  gates_kernel  <<<dim3(256),  dim3(384), 0, stream>>>(outb, W_ih, b_ih, gts);
  gru_cls_kernel<<<dim3(32),   dim3(768), 0, stream>>>(gts, W_hh, b_hh, W1, b1, W2, b2, W3, b3, out);
}

// Round 8
// 425.614 us; speedup vs baseline: 1.4613x; 1.2769x over previous
//
#include <hip/hip_runtime.h>
#include <hip/hip_bf16.h>
#include <math.h>

// Problem sizes (fixed by the reference)
constexpr int Bn  = 32;
constexpr int LK  = 2048;
constexpr int Dn  = 32;
constexpr int LQ  = 128;
constexpr int ET  = 128;
constexpr int Hn  = 8;
constexpr int ETK = 16;
constexpr int NH  = 128;

typedef __attribute__((ext_vector_type(8)))  short bf16x8;
typedef __attribute__((ext_vector_type(16))) float f32x16;

__device__ __forceinline__ float hsum4(float4 v){ return (v.x+v.y)+(v.z+v.w); }
__device__ __forceinline__ void fma4(float4& s, const float4 a, const float4 b){
  s.x = fmaf(a.x,b.x,s.x); s.y = fmaf(a.y,b.y,s.y);
  s.z = fmaf(a.z,b.z,s.z); s.w = fmaf(a.w,b.w,s.w);
}
__device__ __forceinline__ unsigned short bfu(float a){
  __hip_bfloat16 h = __float2bfloat16(a);
  unsigned short u; __builtin_memcpy(&u, &h, 2); return u;
}
__device__ __forceinline__ unsigned pkbf(float a, float b){
  return (unsigned)bfu(a) | ((unsigned)bfu(b) << 16);
}

// ---------------------------------------------------------------------------
// Kernel 0: x (B,LK,32) f32  ->  xT (B,32,LK) bf16.  grid = B*32 (64-key tiles)
// ---------------------------------------------------------------------------
__global__ __launch_bounds__(256) void xt_kernel(
    const float* __restrict__ x, __hip_bfloat16* __restrict__ xT)
{
  __shared__ float tile[32][65];
  const int wg = blockIdx.x;
  const int b = wg >> 5, kt = wg & 31;
  const int k0 = kt*64;
  const int t = threadIdx.x;
  // read 64 keys x 32 d coalesced: thread reads 8 consecutive f32
  const float4* src = (const float4*)(x + ((size_t)b*LK + k0)*Dn);
  const float4 v0 = src[t*2], v1 = src[t*2+1];
  const int r = t>>2, c0 = (t&3)*8;
  tile[c0+0][r]=v0.x; tile[c0+1][r]=v0.y; tile[c0+2][r]=v0.z; tile[c0+3][r]=v0.w;
  tile[c0+4][r]=v1.x; tile[c0+5][r]=v1.y; tile[c0+6][r]=v1.z; tile[c0+7][r]=v1.w;
  __syncthreads();
  const int d = t>>3, o = (t&7)*8;
  uint4 w;
  w.x = pkbf(tile[d][o+0], tile[d][o+1]);
  w.y = pkbf(tile[d][o+2], tile[d][o+3]);
  w.z = pkbf(tile[d][o+4], tile[d][o+5]);
  w.w = pkbf(tile[d][o+6], tile[d][o+7]);
  *(uint4*)(xT + ((size_t)(b*Dn + d))*LK + k0 + o) = w;
}

// ---------------------------------------------------------------------------
// Kernel 1: time embedding + Q/K projection -> bf16.  (0.25 folded into Q)
// grid = 1024 key-WGs (64 rows each) + 2 query-WGs; block = 128.
// ---------------------------------------------------------------------------
__global__ __launch_bounds__(128) void proj_kernel(
    const float* __restrict__ ts, const float* __restrict__ qt,
    const float* __restrict__ Wlin, const float* __restrict__ blin,
    const float* __restrict__ Wper, const float* __restrict__ bper,
    const float* __restrict__ Wq, const float* __restrict__ bq,
    const float* __restrict__ Wk, const float* __restrict__ bk,
    __hip_bfloat16* __restrict__ Kbuf, __hip_bfloat16* __restrict__ Qbuf)
{
  __shared__ __align__(16) float emb[64*ET];
  const int wg  = blockIdx.x;
  const int tid = threadIdx.x;
  const bool isq = (wg >= 1024);
  const int row0 = isq ? (wg - 1024)*64 : wg*64;
  const float* W    = isq ? Wq : Wk;
  const float* bias = isq ? bq : bk;
  const int op = tid >> 1, half = tid & 1;

  float4 w0[16], w1[16];
  {
    const float4* r0 = (const float4*)(W + (2*op  )*ET + half*64);
    const float4* r1 = (const float4*)(W + (2*op+1)*ET + half*64);
    #pragma unroll
    for (int i=0;i<16;i++){ w0[i]=r0[i]; w1[i]=r1[i]; }
  }
  const float bo = bias[tid];

  const float wl = Wlin[0], bl = blin[0];
  float wp = 0.f, bp = 0.f;
  if (tid > 0){ wp = Wper[tid-1]; bp = bper[tid-1]; }
  for (int r=0;r<64;r++){
    const float t = isq ? qt[row0+r] : ts[row0+r];
    emb[r*ET + tid] = (tid==0) ? fmaf(t, wl, bl) : __sinf(fmaf(t, wp, bp));
  }
  __syncthreads();

  for (int r=0;r<64;r++){
    const float4* e4 = (const float4*)(emb + r*ET + half*64);
    float4 a0 = {0,0,0,0}, a1 = {0,0,0,0};
    #pragma unroll
    for (int i=0;i<16;i++){ const float4 e = e4[i]; fma4(a0, w0[i], e); fma4(a1, w1[i], e); }
    float s0 = hsum4(a0), s1 = hsum4(a1);
    s0 += __shfl_xor(s0, 1);
    s1 += __shfl_xor(s1, 1);
    const float s = (half==0 ? s0 : s1) + bo;   // lane tid owns output o==tid
    const int o = tid;
    const int row = row0 + r;
    if (isq){
      Qbuf[((o>>4)*LQ + row)*ETK + (o&15)] = __float2bfloat16(s * 0.25f); // (H,LQ,16)
    } else {
      const int b = row >> 11, lkey = row & (LK-1);
      Kbuf[(((b<<3) + (o>>4))*LK + lkey)*ETK + (o&15)] = __float2bfloat16(s); // (B,H,LK,16)
    }
  }
}

// ---------------------------------------------------------------------------
// Kernel 2: MFMA flash attention.  grid = B*H = 256 WGs, 256 thr = 4 waves.
// Wave = one 32-q tile. Swapped QK^T (S^T = K.Q^T) so softmax is lane-local.
// K and xT double-buffered in LDS (XOR-swizzled 16B units).
// ---------------------------------------------------------------------------
__global__ __launch_bounds__(256, 2) void attn_mfma_kernel(
    const __hip_bfloat16* __restrict__ Kb, const __hip_bfloat16* __restrict__ Qb,
    const __hip_bfloat16* __restrict__ xT, float* __restrict__ attb)
{
  __shared__ uint4 Ks[2][512];    // 256 keys x 16 bf16 (2 units/row)
  __shared__ uint4 Xs[2][1024];   // 32 d x 256 keys (32 units/row)
  const int wgid = blockIdx.x;
  const int b = wgid >> 3, h = wgid & 7;
  const int tid = threadIdx.x;
  const int lane = tid & 63;
  const int ln = lane & 31, hi = lane >> 5;
  const int q0 = (tid >> 6) * 32;

  // B-operand: lane holds Q[q0+ln][8*hi + i]  (16 bf16 per row)
  bf16x8 qf;
  {
    const uint4 u = *(const uint4*)(Qb + ((h*LQ + q0 + ln)*ETK + 8*hi));
    qf = *(const bf16x8*)&u;
  }

  const f32x16 zf = {0.f,0.f,0.f,0.f,0.f,0.f,0.f,0.f,0.f,0.f,0.f,0.f,0.f,0.f,0.f,0.f};
  f32x16 acc = zf;
  float m = -INFINITY, lsum = 0.f;

  const int sd = tid>>3, skb = (tid&7)*4, sdx = sd&7, ksw = (tid>>2)&7;
  const uint4* Kg = (const uint4*)(Kb + ((size_t)(b*Hn + h)*LK)*ETK);
  const uint4* Xg = (const uint4*)(xT + ((size_t)(b*Dn + sd))*LK + (tid&7)*32);

  uint4 kr0, kr1, xr0, xr1, xr2, xr3;
  // prologue: stage chunk 0
  {
    const uint4* kp = Kg + tid*2;
    kr0 = kp[0]; kr1 = kp[1];
    xr0 = Xg[0]; xr1 = Xg[1]; xr2 = Xg[2]; xr3 = Xg[3];
    Ks[0][(2*tid  ) ^ ksw] = kr0;
    Ks[0][(2*tid+1) ^ ksw] = kr1;
    Xs[0][sd*32 + ((skb+0)^sdx)] = xr0;
    Xs[0][sd*32 + ((skb+1)^sdx)] = xr1;
    Xs[0][sd*32 + ((skb+2)^sdx)] = xr2;
    Xs[0][sd*32 + ((skb+3)^sdx)] = xr3;
  }
  __syncthreads();

  for (int ck = 0; ck < 8; ck++){
    const int cur = ck & 1, nxt = cur ^ 1;
    if (ck < 7){
      const uint4* kp = Kg + ((ck+1)*256 + tid)*2;
      kr0 = kp[0]; kr1 = kp[1];
      const uint4* xp = Xg + (ck+1)*32;   // 256 keys = 512 B = 32 uint4 along row
      xr0 = xp[0]; xr1 = xp[1]; xr2 = xp[2]; xr3 = xp[3];
    }

    for (int kt = 0; kt < 8; kt++){
      // A-operand: K rows kt*32+ln, k-half hi
      const int r = kt*32 + ln;
      const uint4 ku = Ks[cur][(2*r + hi) ^ ((r>>2)&7)];
      const bf16x8 kf = *(const bf16x8*)&ku;
      f32x16 s = __builtin_amdgcn_mfma_f32_32x32x16_bf16(kf, qf, zf, 0, 0, 0);

      // online softmax: lane holds 16 keys of this 32-key tile for q=q0+ln
      float tmax = s[0];
      #pragma unroll
      for (int i=1;i<16;i++) tmax = fmaxf(tmax, s[i]);
      tmax = fmaxf(tmax, __shfl_xor(tmax, 32));
      if (__any(tmax > m)){
        const float mn = fmaxf(m, tmax);
        const float al = __expf(m - mn);
        lsum *= al;
        acc *= al;
        m = mn;
      }
      float p[16]; float tsum = 0.f;
      #pragma unroll
      for (int i=0;i<16;i++){ p[i] = __expf(s[i] - m); tsum += p[i]; }
      tsum += __shfl_xor(tsum, 32);
      lsum += tsum;

      // pack P to bf16 and build PV B-fragments via partner exchange
      unsigned w0=pkbf(p[0],p[1]),  w1=pkbf(p[2],p[3]),  w2=pkbf(p[4],p[5]),  w3=pkbf(p[6],p[7]);
      unsigned w4=pkbf(p[8],p[9]),  w5=pkbf(p[10],p[11]),w6=pkbf(p[12],p[13]),w7=pkbf(p[14],p[15]);
      unsigned pw0=__shfl_xor(w0,32), pw1=__shfl_xor(w1,32), pw2=__shfl_xor(w2,32), pw3=__shfl_xor(w3,32);
      unsigned pw4=__shfl_xor(w4,32), pw5=__shfl_xor(w5,32), pw6=__shfl_xor(w6,32), pw7=__shfl_xor(w7,32);
      uint4 fa, fb;
      fa.x = hi ? pw2 : w0;  fa.y = hi ? pw3 : w1;
      fa.z = hi ? w2  : pw0; fa.w = hi ? w3  : pw1;
      fb.x = hi ? pw6 : w4;  fb.y = hi ? pw7 : w5;
      fb.z = hi ? w6  : pw4; fb.w = hi ? w7  : pw5;

      // A-operand: xT[d = ln][keys], two k-halves of the 32-key tile
      const int du = ln*32, dx = ln&7;
      const uint4 xa = Xs[cur][du + ((kt*4 + hi    )^dx)];
      const uint4 xb = Xs[cur][du + ((kt*4 + 2 + hi)^dx)];
      acc = __builtin_amdgcn_mfma_f32_32x32x16_bf16(*(const bf16x8*)&xa, *(const bf16x8*)&fa, acc, 0, 0, 0);
      acc = __builtin_amdgcn_mfma_f32_32x32x16_bf16(*(const bf16x8*)&xb, *(const bf16x8*)&fb, acc, 0, 0, 0);
    }

    if (ck < 7){
      Ks[nxt][(2*tid  ) ^ ksw] = kr0;
      Ks[nxt][(2*tid+1) ^ ksw] = kr1;
      Xs[nxt][sd*32 + ((skb+0)^sdx)] = xr0;
      Xs[nxt][sd*32 + ((skb+1)^sdx)] = xr1;
      Xs[nxt][sd*32 + ((skb+2)^sdx)] = xr2;
      Xs[nxt][sd*32 + ((skb+3)^sdx)] = xr3;
    }
    __syncthreads();
  }

  // epilogue: normalize and store att (b, q, h*32+d); lane q = q0+ln,
  // reg 4g+j -> d = 8g + j + 4*hi
  const float inv = 1.f / lsum;
  float* dst = attb + ((size_t)(b*LQ + q0 + ln)*(Hn*Dn) + h*Dn + 4*hi);
  #pragma unroll
  for (int g=0; g<4; g++){
    float4 v;
    v.x = acc[4*g+0]*inv; v.y = acc[4*g+1]*inv;
    v.z = acc[4*g+2]*inv; v.w = acc[4*g+3]*inv;
    *(float4*)(dst + g*8) = v;
  }
}

// ---------------------------------------------------------------------------
// Kernel 4: out = att @ Wo^T + bo. 16 rows/WG, weight half-rows in VGPRs.
// ---------------------------------------------------------------------------
__global__ __launch_bounds__(256) void outproj_kernel(
    const float* __restrict__ att, const float* __restrict__ Wo, const float* __restrict__ bo,
    float* __restrict__ outb)
{
  __shared__ __align__(16) float a[16*256];   // 16 KB
  const int tid = threadIdx.x;
  const int o = tid>>1, half = tid&1;
  float4 w[32];
  {
    const float4* Wr = (const float4*)(Wo + o*256 + half*128);
    #pragma unroll
    for (int i=0;i<32;i++) w[i]=Wr[i];
  }
  const int row0 = blockIdx.x*16;
  {
    const float4* src = (const float4*)(att + (size_t)row0*256);
    float4* a4 = (float4*)a;
    #pragma unroll
    for (int i=0;i<4;i++) a4[tid + i*256] = src[tid + i*256];
  }
  __syncthreads();
  for (int r=0;r<16;r++){
    const float4* ar = (const float4*)(a + r*256 + half*128);
    float4 s4 = {0,0,0,0};
    #pragma unroll
    for (int i=0;i<32;i++) fma4(s4, w[i], ar[i]);
    float s = hsum4(s4);
    s += __shfl_xor(s, 1);
    if (half==0) outb[(size_t)(row0+r)*NH + o] = s + bo[o];
  }
}

// ---------------------------------------------------------------------------
// Kernel 5: x_gates = out @ W_ih^T + b_ih. 384 threads, full rows in VGPRs.
// ---------------------------------------------------------------------------
__global__ __launch_bounds__(384) void gates_kernel(
    const float* __restrict__ outb, const float* __restrict__ W_ih, const float* __restrict__ b_ih,
    float* __restrict__ gates)
{
  __shared__ __align__(16) float a[16*128];   // 8 KB
  const int tid = threadIdx.x;
  float4 w[32];
  {
    const float4* Wr = (const float4*)(W_ih + (size_t)tid*NH);
    #pragma unroll
    for (int i=0;i<32;i++) w[i]=Wr[i];
  }
  const float bi = b_ih[tid];
  const int row0 = blockIdx.x*16;
  {
    const float4* src = (const float4*)(outb + (size_t)row0*NH);
    float4* a4 = (float4*)a;
    for (int i=tid; i<512; i+=384) a4[i] = src[i];
  }
  __syncthreads();
  for (int r=0;r<16;r++){
    const float4* ar = (const float4*)(a + r*NH);
    float4 s0={0,0,0,0}, s1={0,0,0,0};
    #pragma unroll
    for (int i=0;i<16;i++){ fma4(s0, w[2*i], ar[2*i]); fma4(s1, w[2*i+1], ar[2*i+1]); }
    gates[(size_t)(row0+r)*384 + tid] = hsum4(s0) + hsum4(s1) + bi;
  }
}

// ---------------------------------------------------------------------------
// Kernel 6: GRU scan (128 steps) + classifier MLP, one WG per batch element.
// ---------------------------------------------------------------------------
__global__ __launch_bounds__(768) void gru_cls_kernel(
    const float* __restrict__ gates, const float* __restrict__ W_hh, const float* __restrict__ b_hh,
    const float* __restrict__ W1, const float* __restrict__ b1,
    const float* __restrict__ W2, const float* __restrict__ b2,
    const float* __restrict__ W3, const float* __restrict__ b3,
    float* __restrict__ out)
{
  __shared__ __align__(16) float h[128];
  __shared__ __align__(16) float hg[384];
  __shared__ __align__(16) float c1[304];
  __shared__ __align__(16) float c2[304];
  const int b = blockIdx.x, t = threadIdx.x;
  const int op = t >> 1, half = t & 1;

  float4 w[16];
  {
    const float4* Wr = (const float4*)(W_hh + (size_t)op*NH + half*64);
    #pragma unroll
    for (int i=0;i<16;i++) w[i]=Wr[i];
  }
  const float bh = b_hh[op];

  float gxr=0.f, gxz=0.f, gxn=0.f;
  if (t < 128){
    const size_t gb = (size_t)b*LQ*384 + t;
    gxr = gates[gb]; gxz = gates[gb+128]; gxn = gates[gb+256];
    h[t] = 0.f;
  }
  __syncthreads();

  for (int tt=0; tt<LQ; tt++){
    float nxr=0.f, nxz=0.f, nxn=0.f;
    if (t < 128 && tt+1 < LQ){
      const size_t nb = ((size_t)b*LQ + tt + 1)*384 + t;
      nxr = gates[nb]; nxz = gates[nb+128]; nxn = gates[nb+256];
    }
    const float4* h4 = ((const float4*)h) + half*16;
    float4 s0={0,0,0,0}, s1={0,0,0,0}, s2={0,0,0,0}, s3={0,0,0,0};
    #pragma unroll
    for (int i=0;i<4;i++){
      fma4(s0, w[4*i  ], h4[4*i  ]);
      fma4(s1, w[4*i+1], h4[4*i+1]);
      fma4(s2, w[4*i+2], h4[4*i+2]);
      fma4(s3, w[4*i+3], h4[4*i+3]);
    }
    s0.x+=s1.x; s0.y+=s1.y; s0.z+=s1.z; s0.w+=s1.w;
    s2.x+=s3.x; s2.y+=s3.y; s2.z+=s3.z; s2.w+=s3.w;
    s0.x+=s2.x; s0.y+=s2.y; s0.z+=s2.z; s0.w+=s2.w;
    float s = hsum4(s0);
    s += __shfl_xor(s, 1);
    if (half==0) hg[op] = s + bh;
    __syncthreads();
    if (t < 128){
      const float r = 1.f/(1.f + __expf(-(gxr + hg[t])));
      const float z = 1.f/(1.f + __expf(-(gxz + hg[t+128])));
      const float n = 1.f - 2.f/(1.f + __expf(2.f*fmaf(r, hg[t+256], gxn)));
      h[t] = (1.f - z)*n + z*h[t];
      gxr = nxr; gxz = nxz; gxn = nxn;
    }
    __syncthreads();
  }

  if (t < 300){
    const float4* Wr1 = (const float4*)(W1 + (size_t)t*128);
    const float4* h4 = (const float4*)h;
    float4 s={0,0,0,0};
    #pragma unroll
    for (int i=0;i<32;i++) fma4(s, Wr1[i], h4[i]);
    c1[t] = fmaxf(hsum4(s) + b1[t], 0.f);
  }
  __syncthreads();
  if (t < 300){
    const float4* Wr2 = (const float4*)(W2 + (size_t)t*300);
    const float4* c14 = (const float4*)c1;
    float4 s={0,0,0,0};
    #pragma unroll
    for (int i=0;i<75;i++) fma4(s, Wr2[i], c14[i]);
    c2[t] = fmaxf(hsum4(s) + b2[t], 0.f);
  }
  __syncthreads();
  if (t < 2){
    const float4* Wr3 = (const float4*)(W3 + (size_t)t*300);
    const float4* c24 = (const float4*)c2;
    float4 s={0,0,0,0};
    #pragma unroll
    for (int i=0;i<75;i++) fma4(s, Wr3[i], c24[i]);
    out[b*2 + t] = hsum4(s) + b3[t];
  }
}

// ---------------------------------------------------------------------------
extern "C" void kernel_launch(void* const* d_in, const int* in_sizes, int n_in,
                              void* d_out, int out_size, void* d_ws, size_t ws_size,
                              hipStream_t stream)
{
  const float* x    = (const float*)d_in[0];
  const float* ts   = (const float*)d_in[1];
  const float* qt   = (const float*)d_in[2];
  const float* Wlin = (const float*)d_in[3];
  const float* blin = (const float*)d_in[4];
  const float* Wper = (const float*)d_in[5];
  const float* bper = (const float*)d_in[6];
  const float* Wq   = (const float*)d_in[7];
  const float* bq   = (const float*)d_in[8];
  const float* Wk   = (const float*)d_in[9];
  const float* bk   = (const float*)d_in[10];
  const float* Wo   = (const float*)d_in[11];
  const float* bo   = (const float*)d_in[12];
  const float* W_ih = (const float*)d_in[13];
  const float* b_ih = (const float*)d_in[14];
  const float* W_hh = (const float*)d_in[15];
  const float* b_hh = (const float*)d_in[16];
  const float* W1   = (const float*)d_in[17];
  const float* b1   = (const float*)d_in[18];
  const float* W2   = (const float*)d_in[19];
  const float* b2   = (const float*)d_in[20];
  const float* W3   = (const float*)d_in[21];
  const float* b3   = (const float*)d_in[22];
  float* out = (float*)d_out;

  // workspace layout
  __hip_bfloat16* Kbb = (__hip_bfloat16*)d_ws;            // B*H*LK*16 = 8,388,608 bf16
  __hip_bfloat16* Qbb = Kbb + 8388608;                    // H*LQ*16   = 16,384 bf16
  __hip_bfloat16* xTb = Qbb + 16384;                      // B*32*LK   = 2,097,152 bf16
  float* attb = (float*)(xTb + 2097152);                  // B*LQ*256  = 1,048,576 f32
  float* outb = attb + 1048576;                           // B*LQ*128  = 524,288 f32
  float* gts  = outb + 524288;                            // B*LQ*384  = 1,572,864 f32
  (void)ws_size; (void)in_sizes; (void)n_in; (void)out_size;

  xt_kernel      <<<dim3(1024), dim3(256), 0, stream>>>(x, xTb);
  proj_kernel    <<<dim3(1026), dim3(128), 0, stream>>>(ts, qt, Wlin, blin, Wper, bper, Wq, bq, Wk, bk, Kbb, Qbb);
  attn_mfma_kernel<<<dim3(256), dim3(256), 0, stream>>>(Kbb, Qbb, xTb, attb);
  outproj_kernel <<<dim3(256),  dim3(256), 0, stream>>>(attb, Wo, bo, outb);
  gates_kernel   <<<dim3(256),  dim3(384), 0, stream>>>(outb, W_ih, b_ih, gts);
  gru_cls_kernel <<<dim3(32),   dim3(768), 0, stream>>>(gts, W_hh, b_hh, W1, b1, W2, b2, W3, b3, out);
}